// Round 10
// baseline (298.581 us; speedup 1.0000x reference)
//
#include <hip/hip_runtime.h>
#include <math.h>

#define NROWS 32768
#define CDIM  512
#define G_    2
#define V_    320
#define NCOLS 640
#define DCODE 128
#define NSLOT 64

typedef short bf16x8 __attribute__((ext_vector_type(8)));
typedef float f32x4  __attribute__((ext_vector_type(4)));

__device__ __forceinline__ short f2bf(float f) {
    union { float f; unsigned u; } v; v.f = f;
    unsigned r = v.u + 0x7FFFu + ((v.u >> 16) & 1u);   // RTNE
    return (short)(r >> 16);
}
__device__ __forceinline__ float bf2f(unsigned short u) {
    union { unsigned u; float f; } v; v.u = ((unsigned)u) << 16; return v.f;
}
__device__ __forceinline__ void gl_lds16(const void* g, void* l) {
    __builtin_amdgcn_global_load_lds(
        (const __attribute__((address_space(1))) unsigned int*)g,
        (__attribute__((address_space(3))) unsigned int*)l, 16, 0, 0);
}

// W [512][640] f32 -> wt [640][512] bf16
__global__ __launch_bounds__(256) void wprep(const float* __restrict__ w,
                                             short* __restrict__ wt) {
    int gid = blockIdx.x * 256 + threadIdx.x;
    int k = gid / NCOLS;
    int n = gid - k * NCOLS;
    wt[(size_t)n * CDIM + k] = f2bf(w[(size_t)k * NCOLS + n]);
}

// ---------------- pure GEMM: 128x128 tile, m97 structure ----------------
// 256 thr = 4 waves (wr,wc in 2x2). Wave tile 64x64: acc[4][4] 16x16 frags.
// A: reg-staged f32->bf16->LDS fragment-major. B: global_load_lds from wt.
// Output: biased logits bf16 -> lg[32768][640].
__global__ __launch_bounds__(256, 3) void gvq_gemm(
    const float* __restrict__ hidden,    // [32768][512] f32
    const short* __restrict__ wt,        // [640][512] bf16
    const float* __restrict__ bias,      // [640]
    unsigned short* __restrict__ lg)     // [32768][640] bf16 (biased logits)
{
    __shared__ short A[2][4][128][8];    // [buf][kq][row][e] 8 KB/buf
    __shared__ short Bt[2][4][128][8];   // [buf][kq][n][e]

    const int t    = threadIdx.x;
    const int wave = t >> 6;
    const int lane = t & 63;
    const int l15  = lane & 15;
    const int kq   = lane >> 4;
    const int wr   = wave >> 1;
    const int wc   = wave & 1;
    const int bn   = blockIdx.x;         // 0..4
    const int bm   = blockIdx.y;         // 0..255
    const int m0   = bm * 128, n0 = bn * 128;

    // A chunks for this thread: c = kqa*128 + row, two per thread
    const int kqa0 = t >> 7, ra0 = t & 127;
    const int kqa1 = (t + 256) >> 7, ra1 = t & 127;
    const float* ap0 = hidden + (size_t)(m0 + ra0) * CDIM + kqa0 * 8;
    const float* ap1 = hidden + (size_t)(m0 + ra1) * CDIM + kqa1 * 8;

    f32x4 acc[4][4];
    #pragma unroll
    for (int ai = 0; ai < 4; ++ai)
        #pragma unroll
        for (int bj = 0; bj < 4; ++bj)
            #pragma unroll
            for (int r = 0; r < 4; ++r) acc[ai][bj][r] = 0.f;

    // ---- prologue: stage tile 0 ----
    {
        float4 x0 = *(const float4*)(ap0), x1 = *(const float4*)(ap0 + 4);
        float4 y0 = *(const float4*)(ap1), y1 = *(const float4*)(ap1 + 4);
        #pragma unroll
        for (int i = 0; i < 2; ++i) {
            int id = wave + i * 4, kqb = id >> 1, nh = id & 1;
            gl_lds16(wt + (size_t)(n0 + nh * 64 + lane) * CDIM + kqb * 8,
                     &Bt[0][kqb][nh * 64][0]);
        }
        bf16x8 p, q;
        p[0]=f2bf(x0.x); p[1]=f2bf(x0.y); p[2]=f2bf(x0.z); p[3]=f2bf(x0.w);
        p[4]=f2bf(x1.x); p[5]=f2bf(x1.y); p[6]=f2bf(x1.z); p[7]=f2bf(x1.w);
        q[0]=f2bf(y0.x); q[1]=f2bf(y0.y); q[2]=f2bf(y0.z); q[3]=f2bf(y0.w);
        q[4]=f2bf(y1.x); q[5]=f2bf(y1.y); q[6]=f2bf(y1.z); q[7]=f2bf(y1.w);
        *(bf16x8*)&A[0][kqa0][ra0][0] = p;
        *(bf16x8*)&A[0][kqa1][ra1][0] = q;
    }
    __syncthreads();

    // ---- K loop: 16 tiles of K=32, double-buffered, 1 barrier/tile ----
    for (int ts = 0; ts < 16; ++ts) {
        const int cur = ts & 1, nxt = cur ^ 1;
        float4 x0, x1, y0, y1;
        if (ts < 15) {
            const int kb = (ts + 1) * 32;
            x0 = *(const float4*)(ap0 + kb); x1 = *(const float4*)(ap0 + kb + 4);
            y0 = *(const float4*)(ap1 + kb); y1 = *(const float4*)(ap1 + kb + 4);
            #pragma unroll
            for (int i = 0; i < 2; ++i) {
                int id = wave + i * 4, kqb = id >> 1, nh = id & 1;
                gl_lds16(wt + (size_t)(n0 + nh * 64 + lane) * CDIM + kb + kqb * 8,
                         &Bt[nxt][kqb][nh * 64][0]);
            }
        }
        bf16x8 af[4], bfr[4];
        #pragma unroll
        for (int ai = 0; ai < 4; ++ai)
            af[ai] = *(const bf16x8*)&A[cur][kq][wr * 64 + ai * 16 + l15][0];
        #pragma unroll
        for (int bj = 0; bj < 4; ++bj)
            bfr[bj] = *(const bf16x8*)&Bt[cur][kq][wc * 64 + bj * 16 + l15][0];
        #pragma unroll
        for (int ai = 0; ai < 4; ++ai)
            #pragma unroll
            for (int bj = 0; bj < 4; ++bj)
                acc[ai][bj] = __builtin_amdgcn_mfma_f32_16x16x32_bf16(
                    af[ai], bfr[bj], acc[ai][bj], 0, 0, 0);
        if (ts < 15) {
            bf16x8 p, q;
            p[0]=f2bf(x0.x); p[1]=f2bf(x0.y); p[2]=f2bf(x0.z); p[3]=f2bf(x0.w);
            p[4]=f2bf(x1.x); p[5]=f2bf(x1.y); p[6]=f2bf(x1.z); p[7]=f2bf(x1.w);
            q[0]=f2bf(y0.x); q[1]=f2bf(y0.y); q[2]=f2bf(y0.z); q[3]=f2bf(y0.w);
            q[4]=f2bf(y1.x); q[5]=f2bf(y1.y); q[6]=f2bf(y1.z); q[7]=f2bf(y1.w);
            *(bf16x8*)&A[nxt][kqa0][ra0][0] = p;
            *(bf16x8*)&A[nxt][kqa1][ra1][0] = q;
        }
        __syncthreads();
    }

    // ---- epilogue: + bias, store bf16 logits ----
    // C/D: col = n0 + wc*64 + bj*16 + l15, row = m0 + wr*64 + ai*16 + kq*4 + r
    float bv[4];
    #pragma unroll
    for (int bj = 0; bj < 4; ++bj) bv[bj] = bias[n0 + wc * 64 + bj * 16 + l15];
    #pragma unroll
    for (int ai = 0; ai < 4; ++ai)
        #pragma unroll
        for (int bj = 0; bj < 4; ++bj) {
            const int col = n0 + wc * 64 + bj * 16 + l15;
            #pragma unroll
            for (int r = 0; r < 4; ++r) {
                const int row = m0 + wr * 64 + ai * 16 + kq * 4 + r;
                lg[(size_t)row * NCOLS + col] = (unsigned short)f2bf(acc[ai][bj][r] + bv[bj]);
            }
        }
}

// ---------------- epilogue: softmax-sum + gumbel argmax + gather ----------------
// Block = 16 rows x both groups (32 tasks), 256 thr = 4 waves, 8 tasks/wave.
__global__ __launch_bounds__(256) void gvq_epi(
    const unsigned short* __restrict__ lg,  // [32768][640] bf16 biased logits
    const float* __restrict__ gumbel_u,     // [65536][320] f32
    const float* __restrict__ cv,           // [640][128]
    float* __restrict__ out,                // [32768][256] + perp scalar
    float* __restrict__ gavg)               // [NSLOT][640]
{
    __shared__ float savg[NCOLS];
    const int t    = threadIdx.x;
    const int wave = t >> 6;
    const int lane = t & 63;
    const int m0   = blockIdx.x * 16;

    for (int i = t; i < NCOLS; i += 256) savg[i] = 0.f;
    __syncthreads();

    #pragma unroll
    for (int it = 0; it < 8; ++it) {
        const int task = wave * 8 + it;
        const int r = task >> 1, g = task & 1;
        const int row = m0 + r;
        const unsigned short* zr = lg + (size_t)row * NCOLS + g * V_;
        const float* ur = gumbel_u + ((size_t)row * G_ + g) * V_;

        float e[5], s = 0.f, best = -1e30f; int bi = 0;
        #pragma unroll
        for (int j = 0; j < 5; ++j) {
            const int c = lane + j * 64;
            float z = bf2f(zr[c]);
            float u = ur[c];
            float ee = __expf(fminf(z, 60.f));
            e[j] = ee; s += ee;
            float w = -__logf(u + 1e-10f) + 1e-10f;
            float ratio = ee * __builtin_amdgcn_rcpf(w);   // argmax(z+gumbel) == argmax e/w
            if (ratio > best) { best = ratio; bi = c; }
        }
        #pragma unroll
        for (int o = 1; o < 64; o <<= 1) {
            s += __shfl_xor(s, o);
            float ov = __shfl_xor(best, o);
            int   oi = __shfl_xor(bi, o);
            if (ov > best || (ov == best && oi < bi)) { best = ov; bi = oi; }
        }
        const float inv = 1.f / s;
        #pragma unroll
        for (int j = 0; j < 5; ++j)
            atomicAdd(&savg[g * V_ + lane + j * 64], e[j] * inv);

        float2 cvv = ((const float2*)(cv + ((size_t)g * V_ + bi) * DCODE))[lane];
        ((float2*)(out + (size_t)row * (G_ * DCODE) + g * DCODE))[lane] = cvv;
    }
    __syncthreads();

    float* gslot = gavg + (size_t)(blockIdx.x & (NSLOT - 1)) * NCOLS;
    for (int i = t; i < NCOLS; i += 256) atomicAdd(&gslot[i], savg[i]);
}

__global__ __launch_bounds__(64) void gvq_perp(const float* __restrict__ gavg,
                                               float* __restrict__ out, int nslot)
{
    const int lane = threadIdx.x;
    float s0 = 0.f, s1 = 0.f;
    for (int v = lane; v < V_; v += 64) {
        float p0 = 0.f, p1 = 0.f;
        for (int s = 0; s < nslot; ++s) {
            p0 += gavg[(size_t)s * NCOLS + v];
            p1 += gavg[(size_t)s * NCOLS + V_ + v];
        }
        p0 *= (1.f / NROWS); p1 *= (1.f / NROWS);
        s0 += p0 * logf(p0 + 1e-7f);
        s1 += p1 * logf(p1 + 1e-7f);
    }
    #pragma unroll
    for (int o = 32; o >= 1; o >>= 1) {
        s0 += __shfl_xor(s0, o);
        s1 += __shfl_xor(s1, o);
    }
    if (lane == 0)
        out[(size_t)NROWS * (G_ * DCODE)] = expf(-s0) + expf(-s1);
}

// ---------------- fallback (R1-proven fused path, needs only ~724 KB ws) ----------------
__global__ __launch_bounds__(256, 2) void gvq_main_fb(
    const float* __restrict__ hidden, const float* __restrict__ gumbel_u,
    const short* __restrict__ wt, const float* __restrict__ bias,
    const float* __restrict__ cv, float* __restrict__ out, float* __restrict__ gavg)
{
    typedef float f32x16 __attribute__((ext_vector_type(16)));
    __shared__ float savg[NCOLS];
    const int t = threadIdx.x;
    const int wave = t >> 6, lane = t & 63, l31 = lane & 31, hw = lane >> 5;
    const int g = wave & 1;
    const int m0 = blockIdx.x * 64 + (wave >> 1) * 32;
    for (int i = t; i < NCOLS; i += 256) savg[i] = 0.f;
    __syncthreads();
    f32x16 acc[10];
    #pragma unroll
    for (int tt = 0; tt < 10; ++tt)
        #pragma unroll
        for (int r = 0; r < 16; ++r) acc[tt][r] = 0.f;
    const float* hrow  = hidden + (size_t)(m0 + l31) * CDIM + hw * 8;
    const short* wbase = wt + (size_t)(g * V_ + l31) * CDIM + hw * 8;
    for (int k0 = 0; k0 < CDIM; k0 += 16) {
        float4 h0 = *(const float4*)(hrow + k0);
        float4 h1 = *(const float4*)(hrow + k0 + 4);
        bf16x8 a;
        a[0]=f2bf(h0.x); a[1]=f2bf(h0.y); a[2]=f2bf(h0.z); a[3]=f2bf(h0.w);
        a[4]=f2bf(h1.x); a[5]=f2bf(h1.y); a[6]=f2bf(h1.z); a[7]=f2bf(h1.w);
        bf16x8 b[10];
        #pragma unroll
        for (int tt = 0; tt < 10; ++tt)
            b[tt] = *(const bf16x8*)(wbase + (size_t)tt * 32 * CDIM + k0);
        #pragma unroll
        for (int tt = 0; tt < 10; ++tt)
            acc[tt] = __builtin_amdgcn_mfma_f32_32x32x16_bf16(a, b[tt], acc[tt], 0, 0, 0);
    }
    #pragma unroll
    for (int tt = 0; tt < 10; ++tt) {
        float bv = bias[g * V_ + tt * 32 + l31];
        #pragma unroll
        for (int r = 0; r < 16; ++r) acc[tt][r] += bv;
    }
    float mrow[16], inv[16];
    #pragma unroll
    for (int r = 0; r < 16; ++r) {
        float m = acc[0][r];
        #pragma unroll
        for (int tt = 1; tt < 10; ++tt) m = fmaxf(m, acc[tt][r]);
        #pragma unroll
        for (int o = 1; o <= 16; o <<= 1) m = fmaxf(m, __shfl_xor(m, o));
        mrow[r] = m;
        float ss = 0.f;
        #pragma unroll
        for (int tt = 0; tt < 10; ++tt) ss += __expf(acc[tt][r] - m);
        #pragma unroll
        for (int o = 1; o <= 16; o <<= 1) ss += __shfl_xor(ss, o);
        inv[r] = 1.f / ss;
    }
    float cp[10];
    #pragma unroll
    for (int tt = 0; tt < 10; ++tt) cp[tt] = 0.f;
    #pragma unroll
    for (int r = 0; r < 16; ++r) {
        const int R = (r & 3) + 8 * (r >> 2) + 4 * hw;
        const size_t nrow = (size_t)(m0 + R);
        const float* up = gumbel_u + (nrow * 2 + (size_t)g) * V_;
        float best = -1e30f; int bcol = 0;
        #pragma unroll
        for (int tt = 0; tt < 10; ++tt) {
            float z = acc[tt][r];
            cp[tt] += __expf(z - mrow[r]) * inv[r];
            float u = up[tt * 32 + l31];
            float gum = -__logf(-__logf(u + 1e-10f) + 1e-10f);
            float nv = z + gum;
            if (nv > best) { best = nv; bcol = tt * 32 + l31; }
        }
        #pragma unroll
        for (int o = 1; o <= 16; o <<= 1) {
            float ov = __shfl_xor(best, o);
            int   oc = __shfl_xor(bcol, o);
            if (ov > best || (ov == best && oc < bcol)) { best = ov; bcol = oc; }
        }
        float4 cvv = *(const float4*)(cv + ((size_t)g * V_ + bcol) * DCODE + l31 * 4);
        *(float4*)(out + nrow * (G_ * DCODE) + g * DCODE + l31 * 4) = cvv;
    }
    #pragma unroll
    for (int tt = 0; tt < 10; ++tt)
        atomicAdd(&savg[g * V_ + tt * 32 + l31], cp[tt]);
    __syncthreads();
    for (int i = t; i < NCOLS; i += 256) atomicAdd(&gavg[i], savg[i]);
}

extern "C" void kernel_launch(void* const* d_in, const int* in_sizes, int n_in,
                              void* d_out, int out_size, void* d_ws, size_t ws_size,
                              hipStream_t stream)
{
    const float* hidden = (const float*)d_in[0];
    const float* gu     = (const float*)d_in[1];
    const float* w      = (const float*)d_in[2];
    const float* b      = (const float*)d_in[3];
    const float* cv     = (const float*)d_in[4];
    float* out  = (float*)d_out;
    float* gavg = (float*)d_ws;                       // [64][640] f32 = 160 KB

    const size_t OFF_WT = 163840;
    const size_t OFF_LG = OFF_WT + 655360;
    const size_t NEED   = OFF_LG + (size_t)NROWS * NCOLS * 2;   // ~42.8 MB

    short* wtb = (short*)((char*)d_ws + OFF_WT);

    if (ws_size >= NEED) {
        unsigned short* lg = (unsigned short*)((char*)d_ws + OFF_LG);
        hipMemsetAsync(d_ws, 0, NSLOT * NCOLS * sizeof(float), stream);
        wprep<<<(CDIM * NCOLS) / 256, 256, 0, stream>>>(w, wtb);
        gvq_gemm<<<dim3(NCOLS / 128, NROWS / 128), 256, 0, stream>>>(hidden, wtb, b, lg);
        gvq_epi<<<NROWS / 16, 256, 0, stream>>>(lg, gu, cv, out, gavg);
        gvq_perp<<<1, 64, 0, stream>>>(gavg, out, NSLOT);
    } else {
        hipMemsetAsync(d_ws, 0, NCOLS * sizeof(float), stream);
        wprep<<<(CDIM * NCOLS) / 256, 256, 0, stream>>>(w, wtb);
        gvq_main_fb<<<NROWS / 64, 256, 0, stream>>>(hidden, gu, wtb, b, cv, out, gavg);
        gvq_perp<<<1, 64, 0, stream>>>(gavg, out, 1);
    }
}

// Round 11
// 184.188 us; speedup vs baseline: 1.6211x; 1.6211x over previous
//
#include <hip/hip_runtime.h>
#include <math.h>

#define NROWS 32768
#define CDIM  512
#define G_    2
#define V_    320
#define NCOLS 640
#define DCODE 128
#define NSLOT 64
#define BMR   64   // rows per block

typedef short bf16x4 __attribute__((ext_vector_type(4)));
typedef short bf16x8 __attribute__((ext_vector_type(8)));
typedef float f32x4  __attribute__((ext_vector_type(4)));

__device__ __forceinline__ short f2bf(float f) {
    union { float f; unsigned u; } v; v.f = f;
    unsigned r = v.u + 0x7FFFu + ((v.u >> 16) & 1u);   // RTNE
    return (short)(r >> 16);
}

// W [512][640] f32 -> wpk fragment-packed bf16 (640 KB).
// frag gid = ((g*16+ts)*20 + tt16)*64 + kq*16 + l15, elem e = w[ts*32+kq*8+e][g*320+tt16*16+l15]
__global__ __launch_bounds__(256) void wprep(const float* __restrict__ w,
                                             short* __restrict__ wpk) {
    int gid = blockIdx.x * 256 + threadIdx.x;       // 40960 fragments
    int l15 = gid & 15, kq = (gid >> 4) & 3;
    int rem = gid >> 6;
    int tt16 = rem % 20; rem /= 20;
    int ts = rem & 15, g = rem >> 4;
    int n  = g * V_ + tt16 * 16 + l15;
    int k0 = ts * 32 + kq * 8;
    bf16x8 o;
    #pragma unroll
    for (int e = 0; e < 8; ++e) o[e] = f2bf(w[(size_t)(k0 + e) * NCOLS + n]);
    *(bf16x8*)&wpk[(size_t)gid * 8] = o;
}

// Block = 64 rows x 640 cols. 512 thr = 8 waves; wave cg owns cols cg*80..+80
// (g = cg>>2). Swapped MFMA: D[n][m] = mfma(Wfrag, Hfrag) -> lane owns 4 rows x 20 cols,
// rows lane-local => vectorized gumbel + shallow reductions. H staged whole-K in LDS once;
// W streams from L2 (each frag loaded by exactly one wave). K-loop barrier-free.
__global__ __launch_bounds__(512, 3) void gvq_gemm(
    const float* __restrict__ hidden,    // [32768][512] f32
    const float* __restrict__ gumbel_u,  // [65536][320] f32
    const short* __restrict__ wpk,       // fragment-packed bf16
    const float* __restrict__ bias,      // [640]
    const float* __restrict__ cv,        // [640][128]
    float* __restrict__ out,             // [32768][256] + perp scalar
    float* __restrict__ gavg)            // [NSLOT][640]
{
    __shared__ short H_lds[16][4][BMR][8];   // [ts][kq][row][e] = 64 KB
    __shared__ float s_psum[G_][4][BMR];
    __shared__ float s_bestv[G_][4][BMR];
    __shared__ int   s_besti[G_][4][BMR];

    const int t    = threadIdx.x;
    const int wave = t >> 6;
    const int lane = t & 63;
    const int l15  = lane & 15;
    const int kq   = lane >> 4;
    const int cg   = wave;               // col group: 80 cols
    const int g    = cg >> 2;
    const int tb   = (cg & 3) * 5;       // tt16 base within group g
    const int m0   = blockIdx.x * BMR;

    // ---- stage H: 64 rows x 512 k, f32 -> bf16, fragment-major ----
    {
        const int sr = t & 63;
        #pragma unroll
        for (int i = 0; i < 2; ++i) {
            const int sc = (t >> 6) + i * 8;     // ts = sc
            const float* hsrc = hidden + (size_t)(m0 + sr) * CDIM + sc * 32;
            #pragma unroll
            for (int jp = 0; jp < 4; ++jp) {     // k-chunk kq=jp, 8 elems
                float4 v0 = *(const float4*)(hsrc + jp * 8);
                float4 v1 = *(const float4*)(hsrc + jp * 8 + 4);
                bf16x8 p;
                p[0]=f2bf(v0.x); p[1]=f2bf(v0.y); p[2]=f2bf(v0.z); p[3]=f2bf(v0.w);
                p[4]=f2bf(v1.x); p[5]=f2bf(v1.y); p[6]=f2bf(v1.z); p[7]=f2bf(v1.w);
                *(bf16x8*)&H_lds[sc][jp][sr][0] = p;
            }
        }
    }
    __syncthreads();

    f32x4 acc[5][4];                     // [nf][mf]
    #pragma unroll
    for (int nf = 0; nf < 5; ++nf)
        #pragma unroll
        for (int mf = 0; mf < 4; ++mf)
            #pragma unroll
            for (int r = 0; r < 4; ++r) acc[nf][mf][r] = 0.f;

    const short* wbase = wpk + ((size_t)(g * 16) * 20 + tb) * 512 + (size_t)lane * 8;
    const short* hbase = &H_lds[0][0][0][0] + kq * (BMR * 8) + l15 * 8;

    bf16x8 bw[5];
    #pragma unroll
    for (int nf = 0; nf < 5; ++nf) bw[nf] = *(const bf16x8*)(wbase + nf * 512);

    #pragma unroll
    for (int ts = 0; ts < 16; ++ts) {
        const short* wts = wbase + ts * 10240;
        bf16x8 bn[5];
        if (ts < 15) {
            #pragma unroll
            for (int nf = 0; nf < 5; ++nf)
                bn[nf] = *(const bf16x8*)(wts + 10240 + nf * 512);
        }
        bf16x8 hf[4];
        #pragma unroll
        for (int mf = 0; mf < 4; ++mf)
            hf[mf] = *(const bf16x8*)(hbase + ts * (4 * BMR * 8) + mf * 16 * 8);
        #pragma unroll
        for (int nf = 0; nf < 5; ++nf)
            #pragma unroll
            for (int mf = 0; mf < 4; ++mf)
                acc[nf][mf] = __builtin_amdgcn_mfma_f32_16x16x32_bf16(
                    bw[nf], hf[mf], acc[nf][mf], 0, 0, 0);
        #pragma unroll
        for (int nf = 0; nf < 5; ++nf) bw[nf] = bn[nf];
    }

    // ---- epilogue (lane owns rows m0+mf*16+l15, cols g*320+(tb+nf)*16+kq*4+r) ----
    float4 bv4[5];
    #pragma unroll
    for (int nf = 0; nf < 5; ++nf)
        bv4[nf] = *(const float4*)&bias[g * V_ + (tb + nf) * 16 + kq * 4];

    #pragma unroll
    for (int mf = 0; mf < 4; ++mf) {
        const int row = m0 + mf * 16 + l15;
        const float* up = gumbel_u + ((size_t)row * G_ + g) * V_;
        float s = 0.f, best = -1e30f; int bi = 0;
        #pragma unroll
        for (int nf = 0; nf < 5; ++nf) {
            float4 u4 = *(const float4*)&up[(tb + nf) * 16 + kq * 4];
            #pragma unroll
            for (int r = 0; r < 4; ++r) {
                float z = fminf(acc[nf][mf][r] + bv4[nf][r], 60.f);
                float e = __expf(z);
                acc[nf][mf][r] = e;                        // keep numerator for cp
                s += e;
                float u = (r == 0) ? u4.x : (r == 1) ? u4.y : (r == 2) ? u4.z : u4.w;
                float wv = -__logf(u + 1e-10f) + 1e-10f;
                float ratio = e * __builtin_amdgcn_rcpf(wv);  // argmax(z+gumbel)==argmax e/wv
                const int vi = (tb + nf) * 16 + kq * 4 + r;   // ascending scan -> first-max
                if (ratio > best) { best = ratio; bi = vi; }
            }
        }
        // reduce across kq groups (cols) : lanes l15, l15+16, l15+32, l15+48
        #pragma unroll
        for (int o = 16; o <= 32; o <<= 1) {
            s += __shfl_xor(s, o);
            float ov = __shfl_xor(best, o);
            int   oi = __shfl_xor(bi, o);
            if (ov > best || (ov == best && oi < bi)) { best = ov; bi = oi; }
        }
        if (kq == 0) {                       // lanes 0..15
            s_psum[g][cg & 3][mf * 16 + l15]  = s;
            s_bestv[g][cg & 3][mf * 16 + l15] = best;
            s_besti[g][cg & 3][mf * 16 + l15] = bi;
        }
    }
    __syncthreads();

    // ---- cp: per-lane e*inv summed over its 4 rows, fold l15, atomics (1 per col) ----
    float inv[4];
    #pragma unroll
    for (int mf = 0; mf < 4; ++mf) {
        const int rl = mf * 16 + l15;
        inv[mf] = 1.f / (s_psum[g][0][rl] + s_psum[g][1][rl] +
                         s_psum[g][2][rl] + s_psum[g][3][rl]);
    }
    float cpl[5][4];
    #pragma unroll
    for (int nf = 0; nf < 5; ++nf)
        #pragma unroll
        for (int r = 0; r < 4; ++r) {
            float v = acc[nf][0][r] * inv[0] + acc[nf][1][r] * inv[1]
                    + acc[nf][2][r] * inv[2] + acc[nf][3][r] * inv[3];
            #pragma unroll
            for (int o = 1; o <= 8; o <<= 1) v += __shfl_xor(v, o);
            cpl[nf][r] = v;
        }
    float* gslot = gavg + (size_t)(blockIdx.x & (NSLOT - 1)) * NCOLS;
    if (l15 == 0) {
        #pragma unroll
        for (int nf = 0; nf < 5; ++nf)
            #pragma unroll
            for (int r = 0; r < 4; ++r)
                atomicAdd(&gslot[g * V_ + (tb + nf) * 16 + kq * 4 + r], cpl[nf][r]);
    }

    // ---- winner finalize + codevector gather: 128 (row,g) tasks, 4 threads each ----
    {
        const int task = t >> 2;             // 0..127
        const int seg  = t & 3;
        const int r_   = task >> 1, gg = task & 1;
        float best = s_bestv[gg][0][r_]; int bi = s_besti[gg][0][r_];
        #pragma unroll
        for (int q = 1; q < 4; ++q) {
            float v = s_bestv[gg][q][r_];
            if (v > best) { best = v; bi = s_besti[gg][q][r_]; }
        }
        const float* src = cv + ((size_t)gg * V_ + bi) * DCODE + seg * 32;
        float* dst = out + (size_t)(m0 + r_) * (G_ * DCODE) + gg * DCODE + seg * 32;
        #pragma unroll
        for (int j = 0; j < 8; ++j)
            *(float4*)(dst + j * 4) = *(const float4*)(src + j * 4);
    }
}

__global__ __launch_bounds__(64) void gvq_perp(const float* __restrict__ gavg,
                                               float* __restrict__ out, int nslot)
{
    const int lane = threadIdx.x;
    float s0 = 0.f, s1 = 0.f;
    for (int v = lane; v < V_; v += 64) {
        float p0 = 0.f, p1 = 0.f;
        for (int s = 0; s < nslot; ++s) {
            p0 += gavg[(size_t)s * NCOLS + v];
            p1 += gavg[(size_t)s * NCOLS + V_ + v];
        }
        p0 *= (1.f / NROWS); p1 *= (1.f / NROWS);
        s0 += p0 * logf(p0 + 1e-7f);
        s1 += p1 * logf(p1 + 1e-7f);
    }
    #pragma unroll
    for (int o = 32; o >= 1; o >>= 1) {
        s0 += __shfl_xor(s0, o);
        s1 += __shfl_xor(s1, o);
    }
    if (lane == 0)
        out[(size_t)NROWS * (G_ * DCODE)] = expf(-s0) + expf(-s1);
}

extern "C" void kernel_launch(void* const* d_in, const int* in_sizes, int n_in,
                              void* d_out, int out_size, void* d_ws, size_t ws_size,
                              hipStream_t stream)
{
    const float* hidden = (const float*)d_in[0];
    const float* gu     = (const float*)d_in[1];
    const float* w      = (const float*)d_in[2];
    const float* b      = (const float*)d_in[3];
    const float* cv     = (const float*)d_in[4];
    float* out  = (float*)d_out;
    float* gavg = (float*)d_ws;                       // [NSLOT][640] f32 = 160 KB
    short* wpk  = (short*)((char*)d_ws + 163840);     // 640 KB fragment-packed W

    hipMemsetAsync(d_ws, 0, NSLOT * NCOLS * sizeof(float), stream);
    wprep<<<160, 256, 0, stream>>>(w, wpk);
    gvq_gemm<<<NROWS / BMR, 512, 0, stream>>>(hidden, gu, wpk, b, cv, out, gavg);
    gvq_perp<<<1, 64, 0, stream>>>(gavg, out, NSLOT);
}